// Round 1
// baseline (416.814 us; speedup 1.0000x reference)
//
#include <hip/hip_runtime.h>
#include <stdint.h>

using f32x4  = __attribute__((ext_vector_type(4))) float;
using short8 = __attribute__((ext_vector_type(8))) short;
typedef unsigned short u16;
typedef unsigned int   u32;

// B=8, H=8, L=1024, DM=512, DK=DV=64.  M = B*L = 8192.

static __device__ __forceinline__ u16 f2bf(float f) {
  union { float f; u32 u; } v; v.f = f;
  u32 r = v.u + 0x7fffu + ((v.u >> 16) & 1u);   // RNE
  return (u16)(r >> 16);
}
static __device__ __forceinline__ float bf2f(u16 u) {
  union { u32 u; float f; } v; v.u = ((u32)u) << 16;
  return v.f;
}

// async global->LDS, 16B per lane; LDS dest = wave-uniform base + lane*16
#define GLDS16(g, l) __builtin_amdgcn_global_load_lds( \
    (const __attribute__((address_space(1))) u32*)(g), \
    (__attribute__((address_space(3))) u32*)(l), 16, 0, 0)

// ------- 4 weight transposes in one launch: W [512k][512n] -> Wt [n][k] bf16
__global__ __launch_bounds__(256) void k_wt4(const float* __restrict__ W0, const float* __restrict__ W1,
                                             const float* __restrict__ W2, const float* __restrict__ W3,
                                             u16* __restrict__ T0, u16* __restrict__ T1,
                                             u16* __restrict__ T2, u16* __restrict__ T3) {
  const float* W = (blockIdx.z == 0) ? W0 : (blockIdx.z == 1) ? W1 : (blockIdx.z == 2) ? W2 : W3;
  u16* T = (blockIdx.z == 0) ? T0 : (blockIdx.z == 1) ? T1 : (blockIdx.z == 2) ? T2 : T3;
  __shared__ float t[32][33];
  int tx = threadIdx.x & 31, ty = threadIdx.x >> 5;   // 32 x 8
  int x0 = blockIdx.x * 32, y0 = blockIdx.y * 32;     // x = n, y = k
  #pragma unroll
  for (int i = 0; i < 4; i++)
    t[ty + i*8][tx] = W[(y0 + ty + i*8) * 512 + (x0 + tx)];
  __syncthreads();
  #pragma unroll
  for (int i = 0; i < 4; i++)
    T[(x0 + ty + i*8) * 512 + (y0 + tx)] = f2bf(t[tx][ty + i*8]);
}

// ------------- rel embeddings: relk80 [80][64] (zero-pad rows>=65),
//               relvT [64 dv][96 bucket] (zero-pad buckets>=65) -------------
__global__ __launch_bounds__(256) void k_prep_rel(const float* __restrict__ rk,
                                                  const float* __restrict__ rv,
                                                  u16* __restrict__ relk80,
                                                  u16* __restrict__ relvT) {
  int i = blockIdx.x * 256 + threadIdx.x;
  if (i < 80*64) {
    int row = i >> 6;
    relk80[i] = (row < 65) ? f2bf(rk[i]) : (u16)0;
  }
  int j = i - 80*64;
  if (j >= 0 && j < 64*96) {
    int dv = j / 96, bk = j % 96;
    relvT[j] = (bk < 65) ? f2bf(rv[bk*64 + dv]) : (u16)0;
  }
}

// ------------- fp32 -> bf16 for query/key/value in one launch -------------
__global__ __launch_bounds__(256) void k_cvt3(const float* __restrict__ a, const float* __restrict__ b,
                                              const float* __restrict__ c,
                                              u16* __restrict__ oa, u16* __restrict__ ob,
                                              u16* __restrict__ oc) {
  const float* src = (blockIdx.y == 0) ? a : (blockIdx.y == 1) ? b : c;
  u16* dst = (blockIdx.y == 0) ? oa : (blockIdx.y == 1) ? ob : oc;
  int i = blockIdx.x * 256 + threadIdx.x;
  float4 v = ((const float4*)src)[i];
  ushort4 o;
  o.x = f2bf(v.x); o.y = f2bf(v.y); o.z = f2bf(v.z); o.w = f2bf(v.w);
  ((ushort4*)dst)[i] = o;
}

// ------------- pack rel_matrix | mask<<7 | bf16(rel_mask)<<16 -> u32 -------
__global__ __launch_bounds__(256) void k_pack(const int* __restrict__ rm,
                                              const float* __restrict__ rw,
                                              const unsigned char* __restrict__ mk,
                                              u32* __restrict__ outp) {
  int i = blockIdx.x * 256 + threadIdx.x;     // x4 elements
  int4   r4 = ((const int4*)rm)[i];
  float4 w4 = ((const float4*)rw)[i];
  uchar4 m4 = ((const uchar4*)mk)[i];
  uint4 o;
  o.x = (u32)(r4.x & 63) | (m4.x ? 128u : 0u) | ((u32)f2bf(w4.x) << 16);
  o.y = (u32)(r4.y & 63) | (m4.y ? 128u : 0u) | ((u32)f2bf(w4.y) << 16);
  o.z = (u32)(r4.z & 63) | (m4.z ? 128u : 0u) | ((u32)f2bf(w4.z) << 16);
  o.w = (u32)(r4.w & 63) | (m4.w ? 128u : 0u) | ((u32)f2bf(w4.w) << 16);
  ((uint4*)outp)[i] = o;
}

// ---------------- bf16 MFMA GEMM: C = A[8192,512] @ Wt^T + bias -----------
// A bf16 row-major, Wt [n][k] bf16.  Tile M=128, N=64, BK=32; grid (8,64,z).
// Staging via global_load_lds width=16.  Epilogue: acc -> LDS tile -> WIDE
// contiguous stores.
// mode 0: fp32 out [m][n] direct;  mode 1: bf16 [b,h,l,d];  mode 2: bf16 [b,h,d,l].
struct GArg { const u16* A; const u16* Wt; const float* bias; void* out; int mode; float scale; };

__global__ __launch_bounds__(256) void k_gemm(GArg g0, GArg g1, GArg g2) {
  GArg ar = (blockIdx.z == 0) ? g0 : (blockIdx.z == 1) ? g1 : g2;
  __shared__ u16 As[128*32];   // chunk c (16B) at byte c*16: row=c>>2, slot=c&3
  __shared__ u16 Bs[64*32];
  __shared__ u16 Cs[9216];     // mode1: [128][72] pad; mode2 (transposed): [64][136] pad
  int tid = threadIdx.x, lane = tid & 63, wv = tid >> 6;
  int quad = lane >> 4, l15 = lane & 15;
  int n0 = blockIdx.x * 64, m0 = blockIdx.y * 128;
  int wm = (wv >> 1) * 64, wn = (wv & 1) * 32;
  f32x4 acc[4][2];
  #pragma unroll
  for (int i = 0; i < 4; i++)
    #pragma unroll
    for (int j = 0; j < 2; j++)
      acc[i][j] = (f32x4){0.f, 0.f, 0.f, 0.f};

  const u16* Abase = ar.A  + (size_t)m0 * 512;
  const u16* Bbase = ar.Wt + (size_t)n0 * 512;
  int cA0 = wv * 128, cB0 = wv * 64;      // wave-uniform chunk bases

  for (int k0 = 0; k0 < 512; k0 += 32) {
    #pragma unroll
    for (int i = 0; i < 2; i++) {
      int c = cA0 + i*64 + lane;
      GLDS16(Abase + (c >> 2)*512 + k0 + (c & 3)*8, &As[(cA0 + i*64)*8]);
    }
    {
      int c = cB0 + lane;
      GLDS16(Bbase + (c >> 2)*512 + k0 + (c & 3)*8, &Bs[cB0*8]);
    }
    __syncthreads();
    short8 af[4], bf[2];
    #pragma unroll
    for (int i = 0; i < 4; i++) af[i] = *(const short8*)&As[(wm + i*16 + l15)*32 + quad*8];
    #pragma unroll
    for (int j = 0; j < 2; j++) bf[j] = *(const short8*)&Bs[(wn + j*16 + l15)*32 + quad*8];
    #pragma unroll
    for (int i = 0; i < 4; i++)
      #pragma unroll
      for (int j = 0; j < 2; j++)
        acc[i][j] = __builtin_amdgcn_mfma_f32_16x16x32_bf16(af[i], bf[j], acc[i][j], 0, 0, 0);
    __syncthreads();
  }

  if (ar.mode == 0) {
    #pragma unroll
    for (int i = 0; i < 4; i++)
      #pragma unroll
      for (int j = 0; j < 2; j++) {
        int ncol = n0 + wn + j*16 + l15;
        float bv = ar.bias[ncol];
        #pragma unroll
        for (int r = 0; r < 4; r++) {
          int m = m0 + wm + i*16 + quad*4 + r;
          ((float*)ar.out)[m*512 + ncol] = (acc[i][j][r] + bv) * ar.scale;
        }
      }
  } else {
    // acc -> LDS tile (bias+scale applied)
    #pragma unroll
    for (int i = 0; i < 4; i++)
      #pragma unroll
      for (int j = 0; j < 2; j++) {
        int nloc = wn + j*16 + l15;
        float bv = ar.bias[n0 + nloc];
        #pragma unroll
        for (int r = 0; r < 4; r++) {
          int mloc = wm + i*16 + quad*4 + r;
          float val = (acc[i][j][r] + bv) * ar.scale;
          if (ar.mode == 1) Cs[mloc*72 + nloc] = f2bf(val);
          else              Cs[nloc*136 + mloc] = f2bf(val);
        }
      }
    __syncthreads();
    int bb = m0 >> 10, hh = n0 >> 6, mbase = m0 & 1023;
    u16* outp = (u16*)ar.out;
    if (ar.mode == 1) {
      // [b,h,l,d]: 128 rows x 128B contiguous
      size_t base = ((size_t)(bb*8 + hh)*1024 + mbase)*64;
      #pragma unroll
      for (int p = 0; p < 4; p++) {
        int mloc = (tid >> 3) + p*32, seg = tid & 7;
        *(short8*)(outp + base + (size_t)mloc*64 + seg*8) = *(const short8*)&Cs[mloc*72 + seg*8];
      }
    } else {
      // [b,h,d,l]: 64 rows x 256B contiguous
      size_t base = (size_t)(bb*8 + hh)*64*1024 + mbase;
      #pragma unroll
      for (int p = 0; p < 4; p++) {
        int d = (tid >> 4) + p*16, seg = tid & 15;
        *(short8*)(outp + base + (size_t)d*1024 + seg*8) = *(const short8*)&Cs[d*136 + seg*8];
      }
    }
  }
}

// ---------------- fused attention ----------------
// R6: head-split. Was: 512 blocks, each doing all 8 heads (2 per wave via h2
// loop) -> only 2 blocks/CU, Occupancy 19.5%, VALUBusy 30%, latency-bound.
// Now: blockIdx.y in {0,1} selects head group hg*4..hg*4+3, one head per wave.
// Grid 1024 blocks = 4 blocks/CU; LDS 53KB -> 27KB; per-wave VGPR state halves.
__global__ __launch_bounds__(256, 4) void k_attn(
    const u16* __restrict__ qws, const u16* __restrict__ kws, const u16* __restrict__ vtws,
    const u16* __restrict__ relk80, const u16* __restrict__ relvT,
    const float* __restrict__ tree_emb, const u32* __restrict__ packed,
    u16* __restrict__ ctx) {
  __shared__ u16 qdotL[4*16*68];    // [w][q][bucket]  (band phase only)
  __shared__ u16 PB[4][16*96];      // per-wave banded P
  __shared__ u16 Pl[4][16*40];      // per-wave C->A bridge, stride 40
  __shared__ float treec[256];      // [vocab][w]: head hg*4+w, f32 (skip bf2f)

  int tid = threadIdx.x, lane = tid & 63, wv = tid >> 6;
  int quad = lane >> 4, l15 = lane & 15;
  int b = blockIdx.x & 7, qt = blockIdx.x >> 3;
  int hg = blockIdx.y;
  int q0 = qt * 16;
  int h = hg * 4 + wv;

  if (tid < 256) treec[tid] = tree_emb[(tid >> 2)*8 + hg*4 + (tid & 3)];
  for (int i = tid; i < 4*16*96/2; i += 256) ((u32*)PB)[i] = 0u;

  const u16* qb = qws  + (size_t)(b*8 + h)*(1024*64);
  const u16* kb = kws  + (size_t)(b*8 + h)*(1024*64);
  const u16* vb = vtws + (size_t)(b*8 + h)*(64*1024);
  const u32* pkb = packed + ((size_t)b << 20);

  short8 aQ[2];
  #pragma unroll
  for (int kf = 0; kf < 2; kf++)
    aQ[kf] = *(const short8*)(qb + (q0 + l15)*64 + kf*32 + quad*8);

  float qd0[4], qd64[4];
  #pragma unroll
  for (int t = 0; t < 5; t++) {
    f32x4 C = (f32x4){0.f,0.f,0.f,0.f};
    #pragma unroll
    for (int kf = 0; kf < 2; kf++) {
      short8 bR = *(const short8*)(relk80 + (t*16 + l15)*64 + kf*32 + quad*8);
      C = __builtin_amdgcn_mfma_f32_16x16x32_bf16(aQ[kf], bR, C, 0, 0, 0);
    }
    if (t == 0) {
      #pragma unroll
      for (int r = 0; r < 4; r++) qd0[r] = __shfl(C[r], lane & 48, 64);
    }
    if (t == 4) {
      #pragma unroll
      for (int r = 0; r < 4; r++) qd64[r] = __shfl(C[r], lane & 48, 64);
    }
    int col = t*16 + l15;
    if (col < 65) {
      #pragma unroll
      for (int r = 0; r < 4; r++)
        qdotL[(wv*16 + quad*4 + r)*68 + col] = f2bf(C[r]);
    }
  }
  __syncthreads();

  int t_lo = max(0, (q0 - 31) >> 5);
  int t_hi = min(31, (q0 + 46) >> 5);

  short8 kreg[2][2];
  #pragma unroll
  for (int ct = 0; ct < 2; ct++)
    #pragma unroll
    for (int kf = 0; kf < 2; kf++)
      kreg[ct][kf] = *(const short8*)(kb + (ct*16 + l15)*64 + kf*32 + quad*8);
  u32 pk[8];
  #pragma unroll
  for (int e = 0; e < 8; e++) {
    int ct = e >> 2, r = e & 3;
    pk[e] = pkb[((q0 + quad*4 + r) << 10) + ct*16 + l15];
  }

  f32x4 O[4];
  float rs[4], ts0[4], ts1[4];
  #pragma unroll
  for (int t = 0; t < 4; t++) O[t] = (f32x4){0.f,0.f,0.f,0.f};
  #pragma unroll
  for (int r = 0; r < 4; r++) { rs[r] = 0.f; ts0[r] = 0.f; ts1[r] = 0.f; }

  for (int it = 0; it < 32; ++it) {
    int k0 = it << 5;
    int kn = (it + 1 < 32) ? (k0 + 32) : 0;
    short8 vreg[4];
    #pragma unroll
    for (int t = 0; t < 4; t++)
      vreg[t] = *(const short8*)(vb + (t*16 + l15)*1024 + k0 + quad*8);

    f32x4 S[2];
    #pragma unroll
    for (int ct = 0; ct < 2; ct++) {
      f32x4 c = (f32x4){0.f,0.f,0.f,0.f};
      #pragma unroll
      for (int kf = 0; kf < 2; kf++)
        c = __builtin_amdgcn_mfma_f32_16x16x32_bf16(aQ[kf], kreg[ct][kf], c, 0, 0, 0);
      S[ct] = c;
    }
    #pragma unroll
    for (int ct = 0; ct < 2; ct++)
      #pragma unroll
      for (int kf = 0; kf < 2; kf++)
        kreg[ct][kf] = *(const short8*)(kb + (kn + ct*16 + l15)*64 + kf*32 + quad*8);
    u32 pkc[8];
    #pragma unroll
    for (int e = 0; e < 8; e++) pkc[e] = pk[e];
    #pragma unroll
    for (int e = 0; e < 8; e++) {
      int ct = e >> 2, r = e & 3;
      pk[e] = pkb[((q0 + quad*4 + r) << 10) + kn + ct*16 + l15];
    }

    if (it < t_lo || it > t_hi) {
      bool pre = it < t_lo;
      #pragma unroll
      for (int ct = 0; ct < 2; ct++) {
        #pragma unroll
        for (int r = 0; r < 4; r++) {
          u32 sg = pkc[ct*4 + r];
          float rw = bf2f((u16)(sg >> 16));
          float mb = (sg & 128u) ? -1e30f : 0.f;
          float tb = treec[(sg & 63u)*4 + wv];
          float qv = pre ? qd0[r] : qd64[r];
          float p = __expf(S[ct][r] + qv + tb*rw + mb);
          rs[r]  += p;
          ts0[r] += pre ? p : 0.f;
          ts1[r] += pre ? 0.f : p;
          Pl[wv][(quad*4 + r)*40 + ct*16 + l15] = f2bf(p);
        }
      }
    } else {
      #pragma unroll
      for (int ct = 0; ct < 2; ct++) {
        #pragma unroll
        for (int r = 0; r < 4; r++) {
          int kloc = ct*16 + l15, qloc = quad*4 + r;
          int d = (k0 + kloc) - (q0 + qloc);
          int bucket = min(max(d + 32, 0), 64);
          u32 sg = pkc[ct*4 + r];
          float rw = bf2f((u16)(sg >> 16));
          float mb = (sg & 128u) ? -1e30f : 0.f;
          float tb = treec[(sg & 63u)*4 + wv];
          float qd = bf2f(qdotL[(wv*16 + qloc)*68 + bucket]);
          float p = __expf(S[ct][r] + qd + tb*rw + mb);
          rs[r] += p;
          if (d <= -32)      ts0[r] += p;
          else if (d >= 32)  ts1[r] += p;
          else               PB[wv][qloc*96 + d + 32] = f2bf(p);
          Pl[wv][qloc*40 + kloc] = f2bf(p);
        }
      }
    }

    {
      short8 aP = *(const short8*)&Pl[wv][l15*40 + quad*8];
      #pragma unroll
      for (int t = 0; t < 4; t++)
        O[t] = __builtin_amdgcn_mfma_f32_16x16x32_bf16(aP, vreg[t], O[t], 0, 0, 0);
    }
  }

  #pragma unroll
  for (int m = 1; m < 16; m <<= 1) {
    #pragma unroll
    for (int r = 0; r < 4; r++) {
      rs[r]  += __shfl_xor(rs[r],  m, 64);
      ts0[r] += __shfl_xor(ts0[r], m, 64);
      ts1[r] += __shfl_xor(ts1[r], m, 64);
    }
  }
  if (l15 == 0) {
    #pragma unroll
    for (int r = 0; r < 4; r++) {
      PB[wv][(quad*4 + r)*96 + 0]  = f2bf(ts0[r]);
      PB[wv][(quad*4 + r)*96 + 64] = f2bf(ts1[r]);
    }
  }
  __syncthreads();

  {
    short8 aB[3];
    #pragma unroll
    for (int s = 0; s < 3; s++)
      aB[s] = *(const short8*)&PB[wv][l15*96 + s*32 + quad*8];
    #pragma unroll
    for (int t = 0; t < 4; t++)
      #pragma unroll
      for (int s = 0; s < 3; s++) {
        short8 bRV = *(const short8*)(relvT + (t*16 + l15)*96 + s*32 + quad*8);
        O[t] = __builtin_amdgcn_mfma_f32_16x16x32_bf16(aB[s], bRV, O[t], 0, 0, 0);
      }
  }

  {
    float inv[4];
    #pragma unroll
    for (int r = 0; r < 4; r++) inv[r] = 1.0f / rs[r];
    #pragma unroll
    for (int t = 0; t < 4; t++)
      #pragma unroll
      for (int r = 0; r < 4; r++) {
        int qg = q0 + quad*4 + r;
        ctx[(b*1024 + qg)*512 + h*64 + t*16 + l15] = f2bf(O[t][r] * inv[r]);
      }
  }
}

extern "C" void kernel_launch(void* const* d_in, const int* in_sizes, int n_in,
                              void* d_out, int out_size, void* d_ws, size_t ws_size,
                              hipStream_t stream) {
  const float* key   = (const float*)d_in[0];
  const float* value = (const float*)d_in[1];
  const float* query = (const float*)d_in[2];
  const unsigned char* maskp = (const unsigned char*)d_in[3];
  const int*   relm  = (const int*)d_in[4];
  const float* relw  = (const float*)d_in[5];
  const float* Wk = (const float*)d_in[6];
  const float* bk = (const float*)d_in[7];
  const float* Wq = (const float*)d_in[8];
  const float* bq = (const float*)d_in[9];
  const float* Wv = (const float*)d_in[10];
  const float* bv = (const float*)d_in[11];
  const float* Wo = (const float*)d_in[12];
  const float* bo = (const float*)d_in[13];
  const float* rek = (const float*)d_in[14];
  const float* rev = (const float*)d_in[15];
  const float* te  = (const float*)d_in[16];
  (void)in_sizes; (void)n_in; (void)out_size;

  char* w = (char*)d_ws;
  size_t off = 0;
  auto alloc = [&](size_t bytes) -> void* {
    void* p = w + off; off += (bytes + 255) & ~(size_t)255; return p;
  };
  u16* WkT = (u16*)alloc((size_t)512*512*2);
  u16* WqT = (u16*)alloc((size_t)512*512*2);
  u16* WvT = (u16*)alloc((size_t)512*512*2);
  u16* WoT = (u16*)alloc((size_t)512*512*2);
  u16* qws = (u16*)alloc((size_t)8*8*1024*64*2);   // [B,H,L,64], pre-scaled 1/8
  u16* kws = (u16*)alloc((size_t)8*8*1024*64*2);   // [B,H,L,64]
  u16* vt  = (u16*)alloc((size_t)8*8*1024*64*2);   // [B,H,64,L]
  // 32MB region: first xq/xk/xv (bf16 inputs), later overwritten by packed —
  // safe: stream is serial; QKV gemms consume x* before k_pack writes.
  char* shared32 = (char*)alloc((size_t)8*1024*1024*4);
  u16* xq = (u16*)shared32;
  u16* xk = (u16*)(shared32 + (size_t)8192*512*2);
  u16* xv = (u16*)(shared32 + (size_t)2*8192*512*2);
  u32* packed = (u32*)shared32;
  u16* ctxb = (u16*)alloc((size_t)8192*512*2);     // [B,L,512] bf16
  u16* relk80 = (u16*)alloc((size_t)80*64*2);
  u16* relvT  = (u16*)alloc((size_t)64*96*2);
  if (off > ws_size) return;

  k_wt4<<<dim3(16,16,4), 256, 0, stream>>>(Wk, Wq, Wv, Wo, WkT, WqT, WvT, WoT);
  k_prep_rel<<<44, 256, 0, stream>>>(rek, rev, relk80, relvT);
  k_cvt3<<<dim3(4096,3), 256, 0, stream>>>(query, key, value, xq, xk, xv);

  GArg aq { xq, WqT, bq, (void*)qws, 1, 0.125f };
  GArg ak { xk, WkT, bk, (void*)kws, 1, 1.0f };
  GArg av { xv, WvT, bv, (void*)vt,  2, 1.0f };
  k_gemm<<<dim3(8,64,3), 256, 0, stream>>>(aq, ak, av);

  k_pack<<<8192, 256, 0, stream>>>(relm, relw, maskp, packed);

  k_attn<<<dim3(512,2), 256, 0, stream>>>(qws, kws, vt, relk80, relvT, te, packed, ctxb);

  GArg ao { ctxb, WoT, bo, d_out, 0, 1.0f };
  k_gemm<<<dim3(8,64,1), 256, 0, stream>>>(ao, ao, ao);
}

// Round 2
// 381.875 us; speedup vs baseline: 1.0915x; 1.0915x over previous
//
#include <hip/hip_runtime.h>
#include <stdint.h>

using f32x4  = __attribute__((ext_vector_type(4))) float;
using short8 = __attribute__((ext_vector_type(8))) short;
typedef unsigned short u16;
typedef unsigned int   u32;

// B=8, H=8, L=1024, DM=512, DK=DV=64.  M = B*L = 8192.

static __device__ __forceinline__ u16 f2bf(float f) {
  union { float f; u32 u; } v; v.f = f;
  u32 r = v.u + 0x7fffu + ((v.u >> 16) & 1u);   // RNE
  return (u16)(r >> 16);
}
static __device__ __forceinline__ float bf2f(u16 u) {
  union { u32 u; float f; } v; v.u = ((u32)u) << 16;
  return v.f;
}

// async global->LDS, 16B per lane; LDS dest = wave-uniform base + lane*16
#define GLDS16(g, l) __builtin_amdgcn_global_load_lds( \
    (const __attribute__((address_space(1))) u32*)(g), \
    (__attribute__((address_space(3))) u32*)(l), 16, 0, 0)

// ------- 4 weight transposes in one launch: W [512k][512n] -> Wt [n][k] bf16
__global__ __launch_bounds__(256) void k_wt4(const float* __restrict__ W0, const float* __restrict__ W1,
                                             const float* __restrict__ W2, const float* __restrict__ W3,
                                             u16* __restrict__ T0, u16* __restrict__ T1,
                                             u16* __restrict__ T2, u16* __restrict__ T3) {
  const float* W = (blockIdx.z == 0) ? W0 : (blockIdx.z == 1) ? W1 : (blockIdx.z == 2) ? W2 : W3;
  u16* T = (blockIdx.z == 0) ? T0 : (blockIdx.z == 1) ? T1 : (blockIdx.z == 2) ? T2 : T3;
  __shared__ float t[32][33];
  int tx = threadIdx.x & 31, ty = threadIdx.x >> 5;   // 32 x 8
  int x0 = blockIdx.x * 32, y0 = blockIdx.y * 32;     // x = n, y = k
  #pragma unroll
  for (int i = 0; i < 4; i++)
    t[ty + i*8][tx] = W[(y0 + ty + i*8) * 512 + (x0 + tx)];
  __syncthreads();
  #pragma unroll
  for (int i = 0; i < 4; i++)
    T[(x0 + ty + i*8) * 512 + (y0 + tx)] = f2bf(t[tx][ty + i*8]);
}

// ------------- rel embeddings: relk80 [80][64] (zero-pad rows>=65),
//               relvT [64 dv][96 bucket] (zero-pad buckets>=65) -------------
__global__ __launch_bounds__(256) void k_prep_rel(const float* __restrict__ rk,
                                                  const float* __restrict__ rv,
                                                  u16* __restrict__ relk80,
                                                  u16* __restrict__ relvT) {
  int i = blockIdx.x * 256 + threadIdx.x;
  if (i < 80*64) {
    int row = i >> 6;
    relk80[i] = (row < 65) ? f2bf(rk[i]) : (u16)0;
  }
  int j = i - 80*64;
  if (j >= 0 && j < 64*96) {
    int dv = j / 96, bk = j % 96;
    relvT[j] = (bk < 65) ? f2bf(rv[bk*64 + dv]) : (u16)0;
  }
}

// ------------- fp32 -> bf16 for query/key/value in one launch -------------
__global__ __launch_bounds__(256) void k_cvt3(const float* __restrict__ a, const float* __restrict__ b,
                                              const float* __restrict__ c,
                                              u16* __restrict__ oa, u16* __restrict__ ob,
                                              u16* __restrict__ oc) {
  const float* src = (blockIdx.y == 0) ? a : (blockIdx.y == 1) ? b : c;
  u16* dst = (blockIdx.y == 0) ? oa : (blockIdx.y == 1) ? ob : oc;
  int i = blockIdx.x * 256 + threadIdx.x;
  float4 v = ((const float4*)src)[i];
  ushort4 o;
  o.x = f2bf(v.x); o.y = f2bf(v.y); o.z = f2bf(v.z); o.w = f2bf(v.w);
  ((ushort4*)dst)[i] = o;
}

// ------------- pack rel_matrix | mask<<7 | bf16(rel_mask)<<16 -> u32 -------
__global__ __launch_bounds__(256) void k_pack(const int* __restrict__ rm,
                                              const float* __restrict__ rw,
                                              const unsigned char* __restrict__ mk,
                                              u32* __restrict__ outp) {
  int i = blockIdx.x * 256 + threadIdx.x;     // x4 elements
  int4   r4 = ((const int4*)rm)[i];
  float4 w4 = ((const float4*)rw)[i];
  uchar4 m4 = ((const uchar4*)mk)[i];
  uint4 o;
  o.x = (u32)(r4.x & 63) | (m4.x ? 128u : 0u) | ((u32)f2bf(w4.x) << 16);
  o.y = (u32)(r4.y & 63) | (m4.y ? 128u : 0u) | ((u32)f2bf(w4.y) << 16);
  o.z = (u32)(r4.z & 63) | (m4.z ? 128u : 0u) | ((u32)f2bf(w4.z) << 16);
  o.w = (u32)(r4.w & 63) | (m4.w ? 128u : 0u) | ((u32)f2bf(w4.w) << 16);
  ((uint4*)outp)[i] = o;
}

// ---------------- bf16 MFMA GEMM: C = A[8192,512] @ Wt^T + bias -----------
// A bf16 row-major, Wt [n][k] bf16.  Tile M=128, N=64, BK=32; grid (8,64,z).
// Staging via global_load_lds width=16.  Epilogue: acc -> LDS tile -> WIDE
// contiguous stores.
// mode 0: fp32 out [m][n] direct;  mode 1: bf16 [b,h,l,d];  mode 2: bf16 [b,h,d,l].
struct GArg { const u16* A; const u16* Wt; const float* bias; void* out; int mode; float scale; };

__global__ __launch_bounds__(256) void k_gemm(GArg g0, GArg g1, GArg g2) {
  GArg ar = (blockIdx.z == 0) ? g0 : (blockIdx.z == 1) ? g1 : g2;
  __shared__ u16 As[128*32];   // chunk c (16B) at byte c*16: row=c>>2, slot=c&3
  __shared__ u16 Bs[64*32];
  __shared__ u16 Cs[9216];     // mode1: [128][72] pad; mode2 (transposed): [64][136] pad
  int tid = threadIdx.x, lane = tid & 63, wv = tid >> 6;
  int quad = lane >> 4, l15 = lane & 15;
  int n0 = blockIdx.x * 64, m0 = blockIdx.y * 128;
  int wm = (wv >> 1) * 64, wn = (wv & 1) * 32;
  f32x4 acc[4][2];
  #pragma unroll
  for (int i = 0; i < 4; i++)
    #pragma unroll
    for (int j = 0; j < 2; j++)
      acc[i][j] = (f32x4){0.f, 0.f, 0.f, 0.f};

  const u16* Abase = ar.A  + (size_t)m0 * 512;
  const u16* Bbase = ar.Wt + (size_t)n0 * 512;
  int cA0 = wv * 128, cB0 = wv * 64;      // wave-uniform chunk bases

  for (int k0 = 0; k0 < 512; k0 += 32) {
    #pragma unroll
    for (int i = 0; i < 2; i++) {
      int c = cA0 + i*64 + lane;
      GLDS16(Abase + (c >> 2)*512 + k0 + (c & 3)*8, &As[(cA0 + i*64)*8]);
    }
    {
      int c = cB0 + lane;
      GLDS16(Bbase + (c >> 2)*512 + k0 + (c & 3)*8, &Bs[cB0*8]);
    }
    __syncthreads();
    short8 af[4], bf[2];
    #pragma unroll
    for (int i = 0; i < 4; i++) af[i] = *(const short8*)&As[(wm + i*16 + l15)*32 + quad*8];
    #pragma unroll
    for (int j = 0; j < 2; j++) bf[j] = *(const short8*)&Bs[(wn + j*16 + l15)*32 + quad*8];
    #pragma unroll
    for (int i = 0; i < 4; i++)
      #pragma unroll
      for (int j = 0; j < 2; j++)
        acc[i][j] = __builtin_amdgcn_mfma_f32_16x16x32_bf16(af[i], bf[j], acc[i][j], 0, 0, 0);
    __syncthreads();
  }

  if (ar.mode == 0) {
    #pragma unroll
    for (int i = 0; i < 4; i++)
      #pragma unroll
      for (int j = 0; j < 2; j++) {
        int ncol = n0 + wn + j*16 + l15;
        float bv = ar.bias[ncol];
        #pragma unroll
        for (int r = 0; r < 4; r++) {
          int m = m0 + wm + i*16 + quad*4 + r;
          ((float*)ar.out)[m*512 + ncol] = (acc[i][j][r] + bv) * ar.scale;
        }
      }
  } else {
    // acc -> LDS tile (bias+scale applied)
    #pragma unroll
    for (int i = 0; i < 4; i++)
      #pragma unroll
      for (int j = 0; j < 2; j++) {
        int nloc = wn + j*16 + l15;
        float bv = ar.bias[n0 + nloc];
        #pragma unroll
        for (int r = 0; r < 4; r++) {
          int mloc = wm + i*16 + quad*4 + r;
          float val = (acc[i][j][r] + bv) * ar.scale;
          if (ar.mode == 1) Cs[mloc*72 + nloc] = f2bf(val);
          else              Cs[nloc*136 + mloc] = f2bf(val);
        }
      }
    __syncthreads();
    int bb = m0 >> 10, hh = n0 >> 6, mbase = m0 & 1023;
    u16* outp = (u16*)ar.out;
    if (ar.mode == 1) {
      // [b,h,l,d]: 128 rows x 128B contiguous
      size_t base = ((size_t)(bb*8 + hh)*1024 + mbase)*64;
      #pragma unroll
      for (int p = 0; p < 4; p++) {
        int mloc = (tid >> 3) + p*32, seg = tid & 7;
        *(short8*)(outp + base + (size_t)mloc*64 + seg*8) = *(const short8*)&Cs[mloc*72 + seg*8];
      }
    } else {
      // [b,h,d,l]: 64 rows x 256B contiguous
      size_t base = (size_t)(bb*8 + hh)*64*1024 + mbase;
      #pragma unroll
      for (int p = 0; p < 4; p++) {
        int d = (tid >> 4) + p*16, seg = tid & 15;
        *(short8*)(outp + base + (size_t)d*1024 + seg*8) = *(const short8*)&Cs[d*136 + seg*8];
      }
    }
  }
}

// ---------------- fused attention ----------------
// R7: head-split kept (grid (512,2), one head per wave) but:
//  - __launch_bounds__(256,3): R6's (256,4) forced total regs<=128 -> spill
//    (WRITE_SIZE 42MB of scratch). Cap 170 -> no spill, 3 blocks/CU.
//  - tree bias via register table + ds_bpermute (lane v holds tree[v][h]):
//    kills the 8-way-bank-conflict LDS gather (9.6M conflict cycles).
//  - exp2 domain: Q prescaled by 0.125*log2e in GEMM, tree prescaled by
//    log2e at init -> v_exp without the per-element ln2 multiply.
__global__ __launch_bounds__(256, 3) void k_attn(
    const u16* __restrict__ qws, const u16* __restrict__ kws, const u16* __restrict__ vtws,
    const u16* __restrict__ relk80, const u16* __restrict__ relvT,
    const float* __restrict__ tree_emb, const u32* __restrict__ packed,
    u16* __restrict__ ctx) {
  __shared__ u16 qdotL[4*16*68];    // [w][q][bucket]  (band phase only)
  __shared__ u16 PB[4][16*96];      // per-wave banded P
  __shared__ u16 Pl[4][16*40];      // per-wave C->A bridge, stride 40

  int tid = threadIdx.x, lane = tid & 63, wv = tid >> 6;
  int quad = lane >> 4, l15 = lane & 15;
  int b = blockIdx.x & 7, qt = blockIdx.x >> 3;
  int hg = blockIdx.y;
  int q0 = qt * 16;
  int h = hg * 4 + wv;

  // register tree table: lane v (0..63) holds tree_emb[v][h] * log2e
  float treev = tree_emb[lane * 8 + h] * 1.44269504f;

  for (int i = tid; i < 4*16*96/2; i += 256) ((u32*)PB)[i] = 0u;

  const u16* qb = qws  + (size_t)(b*8 + h)*(1024*64);
  const u16* kb = kws  + (size_t)(b*8 + h)*(1024*64);
  const u16* vb = vtws + (size_t)(b*8 + h)*(64*1024);
  const u32* pkb = packed + ((size_t)b << 20);

  short8 aQ[2];
  #pragma unroll
  for (int kf = 0; kf < 2; kf++)
    aQ[kf] = *(const short8*)(qb + (q0 + l15)*64 + kf*32 + quad*8);

  float qd0[4], qd64[4];
  #pragma unroll
  for (int t = 0; t < 5; t++) {
    f32x4 C = (f32x4){0.f,0.f,0.f,0.f};
    #pragma unroll
    for (int kf = 0; kf < 2; kf++) {
      short8 bR = *(const short8*)(relk80 + (t*16 + l15)*64 + kf*32 + quad*8);
      C = __builtin_amdgcn_mfma_f32_16x16x32_bf16(aQ[kf], bR, C, 0, 0, 0);
    }
    if (t == 0) {
      #pragma unroll
      for (int r = 0; r < 4; r++) qd0[r] = __shfl(C[r], lane & 48, 64);
    }
    if (t == 4) {
      #pragma unroll
      for (int r = 0; r < 4; r++) qd64[r] = __shfl(C[r], lane & 48, 64);
    }
    int col = t*16 + l15;
    if (col < 65) {
      #pragma unroll
      for (int r = 0; r < 4; r++)
        qdotL[(wv*16 + quad*4 + r)*68 + col] = f2bf(C[r]);
    }
  }
  __syncthreads();

  int t_lo = max(0, (q0 - 31) >> 5);
  int t_hi = min(31, (q0 + 46) >> 5);

  short8 kreg[2][2];
  #pragma unroll
  for (int ct = 0; ct < 2; ct++)
    #pragma unroll
    for (int kf = 0; kf < 2; kf++)
      kreg[ct][kf] = *(const short8*)(kb + (ct*16 + l15)*64 + kf*32 + quad*8);
  u32 pk[8];
  #pragma unroll
  for (int e = 0; e < 8; e++) {
    int ct = e >> 2, r = e & 3;
    pk[e] = pkb[((q0 + quad*4 + r) << 10) + ct*16 + l15];
  }

  f32x4 O[4];
  float rs[4], ts0[4], ts1[4];
  #pragma unroll
  for (int t = 0; t < 4; t++) O[t] = (f32x4){0.f,0.f,0.f,0.f};
  #pragma unroll
  for (int r = 0; r < 4; r++) { rs[r] = 0.f; ts0[r] = 0.f; ts1[r] = 0.f; }

  for (int it = 0; it < 32; ++it) {
    int k0 = it << 5;
    int kn = (it + 1 < 32) ? (k0 + 32) : 0;
    short8 vreg[4];
    #pragma unroll
    for (int t = 0; t < 4; t++)
      vreg[t] = *(const short8*)(vb + (t*16 + l15)*1024 + k0 + quad*8);

    f32x4 S[2];
    #pragma unroll
    for (int ct = 0; ct < 2; ct++) {
      f32x4 c = (f32x4){0.f,0.f,0.f,0.f};
      #pragma unroll
      for (int kf = 0; kf < 2; kf++)
        c = __builtin_amdgcn_mfma_f32_16x16x32_bf16(aQ[kf], kreg[ct][kf], c, 0, 0, 0);
      S[ct] = c;
    }
    #pragma unroll
    for (int ct = 0; ct < 2; ct++)
      #pragma unroll
      for (int kf = 0; kf < 2; kf++)
        kreg[ct][kf] = *(const short8*)(kb + (kn + ct*16 + l15)*64 + kf*32 + quad*8);
    u32 pkc[8];
    #pragma unroll
    for (int e = 0; e < 8; e++) pkc[e] = pk[e];
    #pragma unroll
    for (int e = 0; e < 8; e++) {
      int ct = e >> 2, r = e & 3;
      pk[e] = pkb[((q0 + quad*4 + r) << 10) + kn + ct*16 + l15];
    }

    if (it < t_lo || it > t_hi) {
      bool pre = it < t_lo;
      #pragma unroll
      for (int ct = 0; ct < 2; ct++) {
        #pragma unroll
        for (int r = 0; r < 4; r++) {
          u32 sg = pkc[ct*4 + r];
          float rw = bf2f((u16)(sg >> 16));
          float mb = (sg & 128u) ? -1e30f : 0.f;
          float tb = __int_as_float(__builtin_amdgcn_ds_bpermute(
              (int)((sg & 63u) << 2), __float_as_int(treev)));
          float qv = pre ? qd0[r] : qd64[r];
          float p = exp2f(S[ct][r] + qv + tb*rw + mb);
          rs[r]  += p;
          ts0[r] += pre ? p : 0.f;
          ts1[r] += pre ? 0.f : p;
          Pl[wv][(quad*4 + r)*40 + ct*16 + l15] = f2bf(p);
        }
      }
    } else {
      #pragma unroll
      for (int ct = 0; ct < 2; ct++) {
        #pragma unroll
        for (int r = 0; r < 4; r++) {
          int kloc = ct*16 + l15, qloc = quad*4 + r;
          int d = (k0 + kloc) - (q0 + qloc);
          int bucket = min(max(d + 32, 0), 64);
          u32 sg = pkc[ct*4 + r];
          float rw = bf2f((u16)(sg >> 16));
          float mb = (sg & 128u) ? -1e30f : 0.f;
          float tb = __int_as_float(__builtin_amdgcn_ds_bpermute(
              (int)((sg & 63u) << 2), __float_as_int(treev)));
          float qd = bf2f(qdotL[(wv*16 + qloc)*68 + bucket]);
          float p = exp2f(S[ct][r] + qd + tb*rw + mb);
          rs[r] += p;
          if (d <= -32)      ts0[r] += p;
          else if (d >= 32)  ts1[r] += p;
          else               PB[wv][qloc*96 + d + 32] = f2bf(p);
          Pl[wv][qloc*40 + kloc] = f2bf(p);
        }
      }
    }

    {
      short8 aP = *(const short8*)&Pl[wv][l15*40 + quad*8];
      #pragma unroll
      for (int t = 0; t < 4; t++)
        O[t] = __builtin_amdgcn_mfma_f32_16x16x32_bf16(aP, vreg[t], O[t], 0, 0, 0);
    }
  }

  #pragma unroll
  for (int m = 1; m < 16; m <<= 1) {
    #pragma unroll
    for (int r = 0; r < 4; r++) {
      rs[r]  += __shfl_xor(rs[r],  m, 64);
      ts0[r] += __shfl_xor(ts0[r], m, 64);
      ts1[r] += __shfl_xor(ts1[r], m, 64);
    }
  }
  if (l15 == 0) {
    #pragma unroll
    for (int r = 0; r < 4; r++) {
      PB[wv][(quad*4 + r)*96 + 0]  = f2bf(ts0[r]);
      PB[wv][(quad*4 + r)*96 + 64] = f2bf(ts1[r]);
    }
  }
  __syncthreads();

  {
    short8 aB[3];
    #pragma unroll
    for (int s = 0; s < 3; s++)
      aB[s] = *(const short8*)&PB[wv][l15*96 + s*32 + quad*8];
    #pragma unroll
    for (int t = 0; t < 4; t++)
      #pragma unroll
      for (int s = 0; s < 3; s++) {
        short8 bRV = *(const short8*)(relvT + (t*16 + l15)*96 + s*32 + quad*8);
        O[t] = __builtin_amdgcn_mfma_f32_16x16x32_bf16(aB[s], bRV, O[t], 0, 0, 0);
      }
  }

  {
    float inv[4];
    #pragma unroll
    for (int r = 0; r < 4; r++) inv[r] = 1.0f / rs[r];
    #pragma unroll
    for (int t = 0; t < 4; t++)
      #pragma unroll
      for (int r = 0; r < 4; r++) {
        int qg = q0 + quad*4 + r;
        ctx[(b*1024 + qg)*512 + h*64 + t*16 + l15] = f2bf(O[t][r] * inv[r]);
      }
  }
}

extern "C" void kernel_launch(void* const* d_in, const int* in_sizes, int n_in,
                              void* d_out, int out_size, void* d_ws, size_t ws_size,
                              hipStream_t stream) {
  const float* key   = (const float*)d_in[0];
  const float* value = (const float*)d_in[1];
  const float* query = (const float*)d_in[2];
  const unsigned char* maskp = (const unsigned char*)d_in[3];
  const int*   relm  = (const int*)d_in[4];
  const float* relw  = (const float*)d_in[5];
  const float* Wk = (const float*)d_in[6];
  const float* bk = (const float*)d_in[7];
  const float* Wq = (const float*)d_in[8];
  const float* bq = (const float*)d_in[9];
  const float* Wv = (const float*)d_in[10];
  const float* bv = (const float*)d_in[11];
  const float* Wo = (const float*)d_in[12];
  const float* bo = (const float*)d_in[13];
  const float* rek = (const float*)d_in[14];
  const float* rev = (const float*)d_in[15];
  const float* te  = (const float*)d_in[16];
  (void)in_sizes; (void)n_in; (void)out_size;

  char* w = (char*)d_ws;
  size_t off = 0;
  auto alloc = [&](size_t bytes) -> void* {
    void* p = w + off; off += (bytes + 255) & ~(size_t)255; return p;
  };
  u16* WkT = (u16*)alloc((size_t)512*512*2);
  u16* WqT = (u16*)alloc((size_t)512*512*2);
  u16* WvT = (u16*)alloc((size_t)512*512*2);
  u16* WoT = (u16*)alloc((size_t)512*512*2);
  u16* qws = (u16*)alloc((size_t)8*8*1024*64*2);   // [B,H,L,64], pre-scaled 0.125*log2e
  u16* kws = (u16*)alloc((size_t)8*8*1024*64*2);   // [B,H,L,64]
  u16* vt  = (u16*)alloc((size_t)8*8*1024*64*2);   // [B,H,64,L]
  // 32MB region: first xq/xk/xv (bf16 inputs), later overwritten by packed —
  // safe: stream is serial; QKV gemms consume x* before k_pack writes.
  char* shared32 = (char*)alloc((size_t)8*1024*1024*4);
  u16* xq = (u16*)shared32;
  u16* xk = (u16*)(shared32 + (size_t)8192*512*2);
  u16* xv = (u16*)(shared32 + (size_t)2*8192*512*2);
  u32* packed = (u32*)shared32;
  u16* ctxb = (u16*)alloc((size_t)8192*512*2);     // [B,L,512] bf16
  u16* relk80 = (u16*)alloc((size_t)80*64*2);
  u16* relvT  = (u16*)alloc((size_t)64*96*2);
  if (off > ws_size) return;

  k_wt4<<<dim3(16,16,4), 256, 0, stream>>>(Wk, Wq, Wv, Wo, WkT, WqT, WvT, WoT);
  k_prep_rel<<<44, 256, 0, stream>>>(rek, rev, relk80, relvT);
  k_cvt3<<<dim3(4096,3), 256, 0, stream>>>(query, key, value, xq, xk, xv);

  // Q pre-scaled by 0.125 * log2(e): softmax computed in exp2 domain.
  GArg aq { xq, WqT, bq, (void*)qws, 1, 0.18033688f };
  GArg ak { xk, WkT, bk, (void*)kws, 1, 1.0f };
  GArg av { xv, WvT, bv, (void*)vt,  2, 1.0f };
  k_gemm<<<dim3(8,64,3), 256, 0, stream>>>(aq, ak, av);

  k_pack<<<8192, 256, 0, stream>>>(relm, relw, maskp, packed);

  k_attn<<<dim3(512,2), 256, 0, stream>>>(qws, kws, vt, relk80, relvT, te, packed, ctxb);

  GArg ao { ctxb, WoT, bo, d_out, 0, 1.0f };
  k_gemm<<<dim3(8,64,1), 256, 0, stream>>>(ao, ao, ao);
}

// Round 3
// 381.860 us; speedup vs baseline: 1.0915x; 1.0000x over previous
//
#include <hip/hip_runtime.h>
#include <stdint.h>

using f32x4  = __attribute__((ext_vector_type(4))) float;
using short8 = __attribute__((ext_vector_type(8))) short;
typedef unsigned short u16;
typedef unsigned int   u32;

// B=8, H=8, L=1024, DM=512, DK=DV=64.  M = B*L = 8192.

static __device__ __forceinline__ u16 f2bf(float f) {
  union { float f; u32 u; } v; v.f = f;
  u32 r = v.u + 0x7fffu + ((v.u >> 16) & 1u);   // RNE
  return (u16)(r >> 16);
}
static __device__ __forceinline__ float bf2f(u16 u) {
  union { u32 u; float f; } v; v.u = ((u32)u) << 16;
  return v.f;
}

// async global->LDS, 16B per lane; LDS dest = wave-uniform base + lane*16
#define GLDS16(g, l) __builtin_amdgcn_global_load_lds( \
    (const __attribute__((address_space(1))) u32*)(g), \
    (__attribute__((address_space(3))) u32*)(l), 16, 0, 0)

// ------- 4 weight transposes in one launch: W [512k][512n] -> Wt [n][k] bf16
__global__ __launch_bounds__(256) void k_wt4(const float* __restrict__ W0, const float* __restrict__ W1,
                                             const float* __restrict__ W2, const float* __restrict__ W3,
                                             u16* __restrict__ T0, u16* __restrict__ T1,
                                             u16* __restrict__ T2, u16* __restrict__ T3) {
  const float* W = (blockIdx.z == 0) ? W0 : (blockIdx.z == 1) ? W1 : (blockIdx.z == 2) ? W2 : W3;
  u16* T = (blockIdx.z == 0) ? T0 : (blockIdx.z == 1) ? T1 : (blockIdx.z == 2) ? T2 : T3;
  __shared__ float t[32][33];
  int tx = threadIdx.x & 31, ty = threadIdx.x >> 5;   // 32 x 8
  int x0 = blockIdx.x * 32, y0 = blockIdx.y * 32;     // x = n, y = k
  #pragma unroll
  for (int i = 0; i < 4; i++)
    t[ty + i*8][tx] = W[(y0 + ty + i*8) * 512 + (x0 + tx)];
  __syncthreads();
  #pragma unroll
  for (int i = 0; i < 4; i++)
    T[(x0 + ty + i*8) * 512 + (y0 + tx)] = f2bf(t[tx][ty + i*8]);
}

// ------------- rel embeddings: relk80 [80][64] (zero-pad rows>=65),
//               relvT [64 dv][96 bucket] (zero-pad buckets>=65) -------------
__global__ __launch_bounds__(256) void k_prep_rel(const float* __restrict__ rk,
                                                  const float* __restrict__ rv,
                                                  u16* __restrict__ relk80,
                                                  u16* __restrict__ relvT) {
  int i = blockIdx.x * 256 + threadIdx.x;
  if (i < 80*64) {
    int row = i >> 6;
    relk80[i] = (row < 65) ? f2bf(rk[i]) : (u16)0;
  }
  int j = i - 80*64;
  if (j >= 0 && j < 64*96) {
    int dv = j / 96, bk = j % 96;
    relvT[j] = (bk < 65) ? f2bf(rv[bk*64 + dv]) : (u16)0;
  }
}

// ------------- fp32 -> bf16 for query/key/value in one launch -------------
__global__ __launch_bounds__(256) void k_cvt3(const float* __restrict__ a, const float* __restrict__ b,
                                              const float* __restrict__ c,
                                              u16* __restrict__ oa, u16* __restrict__ ob,
                                              u16* __restrict__ oc) {
  const float* src = (blockIdx.y == 0) ? a : (blockIdx.y == 1) ? b : c;
  u16* dst = (blockIdx.y == 0) ? oa : (blockIdx.y == 1) ? ob : oc;
  int i = blockIdx.x * 256 + threadIdx.x;
  float4 v = ((const float4*)src)[i];
  ushort4 o;
  o.x = f2bf(v.x); o.y = f2bf(v.y); o.z = f2bf(v.z); o.w = f2bf(v.w);
  ((ushort4*)dst)[i] = o;
}

// ------------- pack rel_matrix | mask<<7 | bf16(rel_mask)<<16 -> u32 -------
__global__ __launch_bounds__(256) void k_pack(const int* __restrict__ rm,
                                              const float* __restrict__ rw,
                                              const unsigned char* __restrict__ mk,
                                              u32* __restrict__ outp) {
  int i = blockIdx.x * 256 + threadIdx.x;     // x4 elements
  int4   r4 = ((const int4*)rm)[i];
  float4 w4 = ((const float4*)rw)[i];
  uchar4 m4 = ((const uchar4*)mk)[i];
  uint4 o;
  o.x = (u32)(r4.x & 63) | (m4.x ? 128u : 0u) | ((u32)f2bf(w4.x) << 16);
  o.y = (u32)(r4.y & 63) | (m4.y ? 128u : 0u) | ((u32)f2bf(w4.y) << 16);
  o.z = (u32)(r4.z & 63) | (m4.z ? 128u : 0u) | ((u32)f2bf(w4.z) << 16);
  o.w = (u32)(r4.w & 63) | (m4.w ? 128u : 0u) | ((u32)f2bf(w4.w) << 16);
  ((uint4*)outp)[i] = o;
}

// ---------------- bf16 MFMA GEMM: C = A[8192,512] @ Wt^T + bias -----------
struct GArg { const u16* A; const u16* Wt; const float* bias; void* out; int mode; float scale; };

__global__ __launch_bounds__(256) void k_gemm(GArg g0, GArg g1, GArg g2) {
  GArg ar = (blockIdx.z == 0) ? g0 : (blockIdx.z == 1) ? g1 : g2;
  __shared__ u16 As[128*32];   // chunk c (16B) at byte c*16: row=c>>2, slot=c&3
  __shared__ u16 Bs[64*32];
  __shared__ u16 Cs[9216];     // mode1: [128][72] pad; mode2 (transposed): [64][136] pad
  int tid = threadIdx.x, lane = tid & 63, wv = tid >> 6;
  int quad = lane >> 4, l15 = lane & 15;
  int n0 = blockIdx.x * 64, m0 = blockIdx.y * 128;
  int wm = (wv >> 1) * 64, wn = (wv & 1) * 32;
  f32x4 acc[4][2];
  #pragma unroll
  for (int i = 0; i < 4; i++)
    #pragma unroll
    for (int j = 0; j < 2; j++)
      acc[i][j] = (f32x4){0.f, 0.f, 0.f, 0.f};

  const u16* Abase = ar.A  + (size_t)m0 * 512;
  const u16* Bbase = ar.Wt + (size_t)n0 * 512;
  int cA0 = wv * 128, cB0 = wv * 64;      // wave-uniform chunk bases

  for (int k0 = 0; k0 < 512; k0 += 32) {
    #pragma unroll
    for (int i = 0; i < 2; i++) {
      int c = cA0 + i*64 + lane;
      GLDS16(Abase + (c >> 2)*512 + k0 + (c & 3)*8, &As[(cA0 + i*64)*8]);
    }
    {
      int c = cB0 + lane;
      GLDS16(Bbase + (c >> 2)*512 + k0 + (c & 3)*8, &Bs[cB0*8]);
    }
    __syncthreads();
    short8 af[4], bf[2];
    #pragma unroll
    for (int i = 0; i < 4; i++) af[i] = *(const short8*)&As[(wm + i*16 + l15)*32 + quad*8];
    #pragma unroll
    for (int j = 0; j < 2; j++) bf[j] = *(const short8*)&Bs[(wn + j*16 + l15)*32 + quad*8];
    #pragma unroll
    for (int i = 0; i < 4; i++)
      #pragma unroll
      for (int j = 0; j < 2; j++)
        acc[i][j] = __builtin_amdgcn_mfma_f32_16x16x32_bf16(af[i], bf[j], acc[i][j], 0, 0, 0);
    __syncthreads();
  }

  if (ar.mode == 0) {
    #pragma unroll
    for (int i = 0; i < 4; i++)
      #pragma unroll
      for (int j = 0; j < 2; j++) {
        int ncol = n0 + wn + j*16 + l15;
        float bv = ar.bias[ncol];
        #pragma unroll
        for (int r = 0; r < 4; r++) {
          int m = m0 + wm + i*16 + quad*4 + r;
          ((float*)ar.out)[m*512 + ncol] = (acc[i][j][r] + bv) * ar.scale;
        }
      }
  } else {
    #pragma unroll
    for (int i = 0; i < 4; i++)
      #pragma unroll
      for (int j = 0; j < 2; j++) {
        int nloc = wn + j*16 + l15;
        float bv = ar.bias[n0 + nloc];
        #pragma unroll
        for (int r = 0; r < 4; r++) {
          int mloc = wm + i*16 + quad*4 + r;
          float val = (acc[i][j][r] + bv) * ar.scale;
          if (ar.mode == 1) Cs[mloc*72 + nloc] = f2bf(val);
          else              Cs[nloc*136 + mloc] = f2bf(val);
        }
      }
    __syncthreads();
    int bb = m0 >> 10, hh = n0 >> 6, mbase = m0 & 1023;
    u16* outp = (u16*)ar.out;
    if (ar.mode == 1) {
      size_t base = ((size_t)(bb*8 + hh)*1024 + mbase)*64;
      #pragma unroll
      for (int p = 0; p < 4; p++) {
        int mloc = (tid >> 3) + p*32, seg = tid & 7;
        *(short8*)(outp + base + (size_t)mloc*64 + seg*8) = *(const short8*)&Cs[mloc*72 + seg*8];
      }
    } else {
      size_t base = (size_t)(bb*8 + hh)*64*1024 + mbase;
      #pragma unroll
      for (int p = 0; p < 4; p++) {
        int d = (tid >> 4) + p*16, seg = tid & 15;
        *(short8*)(outp + base + (size_t)d*1024 + seg*8) = *(const short8*)&Cs[d*136 + seg*8];
      }
    }
  }
}

// ---------------- fused attention ----------------
// R8: software-pipelined k-loop. At iter jt: QK MFMAs for tile jt+1 issue
// FIRST (fills matrix pipe), softmax VALU for tile jt runs underneath, then
// PV MFMAs for jt. Removes the per-iter S-MFMA->use stall (R7: VALUBusy 38%,
// MfmaUtil 5%, 62% idle at 4 waves/SIMD grid cap -> must hide latency
// in-wave). Loop split into far-pre / band / far-post uniform phases:
// - far phases: single ts accumulator, no per-element selects, no rs add
//   (rs reconstructed exactly as rs_band + ts0 + ts1).
// - band: exactly one accumulator add per element (rs only for in-band).
// Micro: rw = bitcast(sg & 0xffff0000); mask folded into qv cndmask.
// s_setprio(1) around MFMA clusters (m191 attn +4-7%).
__global__ __launch_bounds__(256, 3) void k_attn(
    const u16* __restrict__ qws, const u16* __restrict__ kws, const u16* __restrict__ vtws,
    const u16* __restrict__ relk80, const u16* __restrict__ relvT,
    const float* __restrict__ tree_emb, const u32* __restrict__ packed,
    u16* __restrict__ ctx) {
  __shared__ u16 qdotL[4*16*68];    // [w][q][bucket]  (band phase only)
  __shared__ u16 PB[4][16*96];      // per-wave banded P
  __shared__ u16 Pl[4][16*40];      // per-wave C->A bridge, stride 40

  int tid = threadIdx.x, lane = tid & 63, wv = tid >> 6;
  int quad = lane >> 4, l15 = lane & 15;
  int b = blockIdx.x & 7, qt = blockIdx.x >> 3;
  int hg = blockIdx.y;
  int q0 = qt * 16;
  int h = hg * 4 + wv;

  // register tree table: lane v (0..63) holds tree_emb[v][h] * log2e
  float treev = tree_emb[lane * 8 + h] * 1.44269504f;

  for (int i = tid; i < 4*16*96/2; i += 256) ((u32*)PB)[i] = 0u;

  const u16* qb = qws  + (size_t)(b*8 + h)*(1024*64);
  const u16* kb = kws  + (size_t)(b*8 + h)*(1024*64);
  const u16* vb = vtws + (size_t)(b*8 + h)*(64*1024);
  const u32* pkb = packed + ((size_t)b << 20);

  short8 aQ[2];
  #pragma unroll
  for (int kf = 0; kf < 2; kf++)
    aQ[kf] = *(const short8*)(qb + (q0 + l15)*64 + kf*32 + quad*8);

  float qd0[4], qd64[4];
  #pragma unroll
  for (int t = 0; t < 5; t++) {
    f32x4 C = (f32x4){0.f,0.f,0.f,0.f};
    #pragma unroll
    for (int kf = 0; kf < 2; kf++) {
      short8 bR = *(const short8*)(relk80 + (t*16 + l15)*64 + kf*32 + quad*8);
      C = __builtin_amdgcn_mfma_f32_16x16x32_bf16(aQ[kf], bR, C, 0, 0, 0);
    }
    if (t == 0) {
      #pragma unroll
      for (int r = 0; r < 4; r++) qd0[r] = __shfl(C[r], lane & 48, 64);
    }
    if (t == 4) {
      #pragma unroll
      for (int r = 0; r < 4; r++) qd64[r] = __shfl(C[r], lane & 48, 64);
    }
    int col = t*16 + l15;
    if (col < 65) {
      #pragma unroll
      for (int r = 0; r < 4; r++)
        qdotL[(wv*16 + quad*4 + r)*68 + col] = f2bf(C[r]);
    }
  }
  __syncthreads();

  int t_lo = max(0, (q0 - 31) >> 5);
  int t_hi = min(31, (q0 + 46) >> 5);

  // ---- pipeline prologue: S for tile 0; prefetch K(1), sg(0->pkc, 1->pk)
  short8 kreg[2][2];
  #pragma unroll
  for (int ct = 0; ct < 2; ct++)
    #pragma unroll
    for (int kf = 0; kf < 2; kf++)
      kreg[ct][kf] = *(const short8*)(kb + (ct*16 + l15)*64 + kf*32 + quad*8);
  u32 pk[8];
  #pragma unroll
  for (int e = 0; e < 8; e++) {
    int ct = e >> 2, r = e & 3;
    pk[e] = pkb[((q0 + quad*4 + r) << 10) + ct*16 + l15];
  }

  f32x4 Scur[2];
  #pragma unroll
  for (int ct = 0; ct < 2; ct++) {
    f32x4 c = (f32x4){0.f,0.f,0.f,0.f};
    #pragma unroll
    for (int kf = 0; kf < 2; kf++)
      c = __builtin_amdgcn_mfma_f32_16x16x32_bf16(aQ[kf], kreg[ct][kf], c, 0, 0, 0);
    Scur[ct] = c;
  }
  #pragma unroll
  for (int ct = 0; ct < 2; ct++)
    #pragma unroll
    for (int kf = 0; kf < 2; kf++)
      kreg[ct][kf] = *(const short8*)(kb + (32 + ct*16 + l15)*64 + kf*32 + quad*8);
  u32 pkc[8];
  #pragma unroll
  for (int e = 0; e < 8; e++) pkc[e] = pk[e];
  #pragma unroll
  for (int e = 0; e < 8; e++) {
    int ct = e >> 2, r = e & 3;
    pk[e] = pkb[((q0 + quad*4 + r) << 10) + 32 + ct*16 + l15];
  }

  f32x4 O[4];
  float rs[4], ts0[4], ts1[4];
  #pragma unroll
  for (int t = 0; t < 4; t++) O[t] = (f32x4){0.f,0.f,0.f,0.f};
  #pragma unroll
  for (int r = 0; r < 4; r++) { rs[r] = 0.f; ts0[r] = 0.f; ts1[r] = 0.f; }

  for (int jt = 0; jt < 32; ++jt) {
    int k0 = jt << 5;
    // V for current tile (consumed at PV below; latency covered by softmax)
    short8 vreg[4];
    #pragma unroll
    for (int t = 0; t < 4; t++)
      vreg[t] = *(const short8*)(vb + (t*16 + l15)*1024 + k0 + quad*8);

    // S for NEXT tile (uses kreg prefetched last iter); then K prefetch jt+2
    f32x4 Sn0, Sn1;
    if (jt < 31) {
      __builtin_amdgcn_s_setprio(1);
      {
        f32x4 c = (f32x4){0.f,0.f,0.f,0.f};
        #pragma unroll
        for (int kf = 0; kf < 2; kf++)
          c = __builtin_amdgcn_mfma_f32_16x16x32_bf16(aQ[kf], kreg[0][kf], c, 0, 0, 0);
        Sn0 = c;
        c = (f32x4){0.f,0.f,0.f,0.f};
        #pragma unroll
        for (int kf = 0; kf < 2; kf++)
          c = __builtin_amdgcn_mfma_f32_16x16x32_bf16(aQ[kf], kreg[1][kf], c, 0, 0, 0);
        Sn1 = c;
      }
      __builtin_amdgcn_s_setprio(0);
      int k2 = (jt + 2 < 32) ? ((jt + 2) << 5) : 0;
      #pragma unroll
      for (int ct = 0; ct < 2; ct++)
        #pragma unroll
        for (int kf = 0; kf < 2; kf++)
          kreg[ct][kf] = *(const short8*)(kb + (k2 + ct*16 + l15)*64 + kf*32 + quad*8);
    }

    // ---- softmax for tile jt (Scur, pkc) under the matrix pipe
    if (jt < t_lo) {
      #pragma unroll
      for (int ct = 0; ct < 2; ct++) {
        #pragma unroll
        for (int r = 0; r < 4; r++) {
          u32 sg = pkc[ct*4 + r];
          float rw = __uint_as_float(sg & 0xffff0000u);
          float tb = __int_as_float(__builtin_amdgcn_ds_bpermute(
              (int)((sg & 63u) << 2), __float_as_int(treev)));
          float qm = (sg & 128u) ? -1e30f : qd0[r];
          float p = exp2f(__builtin_fmaf(tb, rw, Scur[ct][r] + qm));
          ts0[r] += p;
          Pl[wv][(quad*4 + r)*40 + ct*16 + l15] = f2bf(p);
        }
      }
    } else if (jt > t_hi) {
      #pragma unroll
      for (int ct = 0; ct < 2; ct++) {
        #pragma unroll
        for (int r = 0; r < 4; r++) {
          u32 sg = pkc[ct*4 + r];
          float rw = __uint_as_float(sg & 0xffff0000u);
          float tb = __int_as_float(__builtin_amdgcn_ds_bpermute(
              (int)((sg & 63u) << 2), __float_as_int(treev)));
          float qm = (sg & 128u) ? -1e30f : qd64[r];
          float p = exp2f(__builtin_fmaf(tb, rw, Scur[ct][r] + qm));
          ts1[r] += p;
          Pl[wv][(quad*4 + r)*40 + ct*16 + l15] = f2bf(p);
        }
      }
    } else {
      #pragma unroll
      for (int ct = 0; ct < 2; ct++) {
        #pragma unroll
        for (int r = 0; r < 4; r++) {
          int kloc = ct*16 + l15, qloc = quad*4 + r;
          int d = (k0 + kloc) - (q0 + qloc);
          int bucket = min(max(d + 32, 0), 64);
          u32 sg = pkc[ct*4 + r];
          float rw = __uint_as_float(sg & 0xffff0000u);
          float tb = __int_as_float(__builtin_amdgcn_ds_bpermute(
              (int)((sg & 63u) << 2), __float_as_int(treev)));
          float qd = bf2f(qdotL[(wv*16 + qloc)*68 + bucket]);
          float qm = (sg & 128u) ? -1e30f : qd;
          float p = exp2f(__builtin_fmaf(tb, rw, Scur[ct][r] + qm));
          if (d <= -32)      ts0[r] += p;
          else if (d >= 32)  ts1[r] += p;
          else             { rs[r] += p; PB[wv][qloc*96 + d + 32] = f2bf(p); }
          Pl[wv][qloc*40 + kloc] = f2bf(p);
        }
      }
    }

    // rotate sg: pkc <- tile jt+1, prefetch tile jt+2
    #pragma unroll
    for (int e = 0; e < 8; e++) pkc[e] = pk[e];
    {
      int kp = (jt + 2 < 32) ? ((jt + 2) << 5) : 0;
      #pragma unroll
      for (int e = 0; e < 8; e++) {
        int ct = e >> 2, r = e & 3;
        pk[e] = pkb[((q0 + quad*4 + r) << 10) + kp + ct*16 + l15];
      }
    }

    // ---- PV for tile jt
    {
      short8 aP = *(const short8*)&Pl[wv][l15*40 + quad*8];
      __builtin_amdgcn_s_setprio(1);
      #pragma unroll
      for (int t = 0; t < 4; t++)
        O[t] = __builtin_amdgcn_mfma_f32_16x16x32_bf16(aP, vreg[t], O[t], 0, 0, 0);
      __builtin_amdgcn_s_setprio(0);
    }

    if (jt < 31) { Scur[0] = Sn0; Scur[1] = Sn1; }
  }

  #pragma unroll
  for (int m = 1; m < 16; m <<= 1) {
    #pragma unroll
    for (int r = 0; r < 4; r++) {
      rs[r]  += __shfl_xor(rs[r],  m, 64);
      ts0[r] += __shfl_xor(ts0[r], m, 64);
      ts1[r] += __shfl_xor(ts1[r], m, 64);
    }
  }
  if (l15 == 0) {
    #pragma unroll
    for (int r = 0; r < 4; r++) {
      PB[wv][(quad*4 + r)*96 + 0]  = f2bf(ts0[r]);
      PB[wv][(quad*4 + r)*96 + 64] = f2bf(ts1[r]);
    }
  }
  __syncthreads();

  {
    short8 aB[3];
    #pragma unroll
    for (int s = 0; s < 3; s++)
      aB[s] = *(const short8*)&PB[wv][l15*96 + s*32 + quad*8];
    #pragma unroll
    for (int t = 0; t < 4; t++)
      #pragma unroll
      for (int s = 0; s < 3; s++) {
        short8 bRV = *(const short8*)(relvT + (t*16 + l15)*96 + s*32 + quad*8);
        O[t] = __builtin_amdgcn_mfma_f32_16x16x32_bf16(aB[s], bRV, O[t], 0, 0, 0);
      }
  }

  {
    float inv[4];
    #pragma unroll
    for (int r = 0; r < 4; r++) inv[r] = 1.0f / (rs[r] + ts0[r] + ts1[r]);
    #pragma unroll
    for (int t = 0; t < 4; t++)
      #pragma unroll
      for (int r = 0; r < 4; r++) {
        int qg = q0 + quad*4 + r;
        ctx[(b*1024 + qg)*512 + h*64 + t*16 + l15] = f2bf(O[t][r] * inv[r]);
      }
  }
}

extern "C" void kernel_launch(void* const* d_in, const int* in_sizes, int n_in,
                              void* d_out, int out_size, void* d_ws, size_t ws_size,
                              hipStream_t stream) {
  const float* key   = (const float*)d_in[0];
  const float* value = (const float*)d_in[1];
  const float* query = (const float*)d_in[2];
  const unsigned char* maskp = (const unsigned char*)d_in[3];
  const int*   relm  = (const int*)d_in[4];
  const float* relw  = (const float*)d_in[5];
  const float* Wk = (const float*)d_in[6];
  const float* bk = (const float*)d_in[7];
  const float* Wq = (const float*)d_in[8];
  const float* bq = (const float*)d_in[9];
  const float* Wv = (const float*)d_in[10];
  const float* bv = (const float*)d_in[11];
  const float* Wo = (const float*)d_in[12];
  const float* bo = (const float*)d_in[13];
  const float* rek = (const float*)d_in[14];
  const float* rev = (const float*)d_in[15];
  const float* te  = (const float*)d_in[16];
  (void)in_sizes; (void)n_in; (void)out_size;

  char* w = (char*)d_ws;
  size_t off = 0;
  auto alloc = [&](size_t bytes) -> void* {
    void* p = w + off; off += (bytes + 255) & ~(size_t)255; return p;
  };
  u16* WkT = (u16*)alloc((size_t)512*512*2);
  u16* WqT = (u16*)alloc((size_t)512*512*2);
  u16* WvT = (u16*)alloc((size_t)512*512*2);
  u16* WoT = (u16*)alloc((size_t)512*512*2);
  u16* qws = (u16*)alloc((size_t)8*8*1024*64*2);   // [B,H,L,64], pre-scaled 0.125*log2e
  u16* kws = (u16*)alloc((size_t)8*8*1024*64*2);   // [B,H,L,64]
  u16* vt  = (u16*)alloc((size_t)8*8*1024*64*2);   // [B,H,64,L]
  // 32MB region: first xq/xk/xv (bf16 inputs), later overwritten by packed —
  // safe: stream is serial; QKV gemms consume x* before k_pack writes.
  char* shared32 = (char*)alloc((size_t)8*1024*1024*4);
  u16* xq = (u16*)shared32;
  u16* xk = (u16*)(shared32 + (size_t)8192*512*2);
  u16* xv = (u16*)(shared32 + (size_t)2*8192*512*2);
  u32* packed = (u32*)shared32;
  u16* ctxb = (u16*)alloc((size_t)8192*512*2);     // [B,L,512] bf16
  u16* relk80 = (u16*)alloc((size_t)80*64*2);
  u16* relvT  = (u16*)alloc((size_t)64*96*2);
  if (off > ws_size) return;

  k_wt4<<<dim3(16,16,4), 256, 0, stream>>>(Wk, Wq, Wv, Wo, WkT, WqT, WvT, WoT);
  k_prep_rel<<<44, 256, 0, stream>>>(rek, rev, relk80, relvT);
  k_cvt3<<<dim3(4096,3), 256, 0, stream>>>(query, key, value, xq, xk, xv);

  // Q pre-scaled by 0.125 * log2(e): softmax computed in exp2 domain.
  GArg aq { xq, WqT, bq, (void*)qws, 1, 0.18033688f };
  GArg ak { xk, WkT, bk, (void*)kws, 1, 1.0f };
  GArg av { xv, WvT, bv, (void*)vt,  2, 1.0f };
  k_gemm<<<dim3(8,64,3), 256, 0, stream>>>(aq, ak, av);

  k_pack<<<8192, 256, 0, stream>>>(relm, relw, maskp, packed);

  k_attn<<<dim3(512,2), 256, 0, stream>>>(qws, kws, vt, relk80, relvT, te, packed, ctxb);

  GArg ao { ctxb, WoT, bo, d_out, 0, 1.0f };
  k_gemm<<<dim3(8,64,1), 256, 0, stream>>>(ao, ao, ao);
}